// Round 5
// baseline (535.292 us; speedup 1.0000x reference)
//
#include <hip/hip_runtime.h>
#include <math.h>

#define NN 50000
#define NE 800000
#define EPSV 1e-5f
#define SCAN_NB 49   // ceil(NN / 1024)

// ---------------- degree count ----------------
__global__ void deg_kernel(const int* __restrict__ dst, int* __restrict__ deg, int E) {
    int e = blockIdx.x * blockDim.x + threadIdx.x;
    if (e < E) atomicAdd(&deg[dst[e]], 1);
}

// ---------------- 3-phase grid-wide exclusive scan of deg -> rowptr, cursor ----------------
__global__ void scan_phaseA(const int* __restrict__ deg, int* __restrict__ blocksum) {
    __shared__ int wsums[4];
    int t = threadIdx.x;
    int base = blockIdx.x * 1024 + t * 4;
    int s = 0;
    if (base + 3 < NN) {
        int4 d = *reinterpret_cast<const int4*>(deg + base);
        s = d.x + d.y + d.z + d.w;
    } else {
        for (int j = 0; j < 4; ++j) if (base + j < NN) s += deg[base + j];
    }
#pragma unroll
    for (int o = 1; o < 64; o <<= 1) s += __shfl_xor(s, o, 64);
    if ((t & 63) == 0) wsums[t >> 6] = s;
    __syncthreads();
    if (t == 0) blocksum[blockIdx.x] = wsums[0] + wsums[1] + wsums[2] + wsums[3];
}

__global__ void scan_phaseB(int* __restrict__ blocksum) {
    int t = threadIdx.x;  // 64 threads
    int v = (t < SCAN_NB) ? blocksum[t] : 0;
    int incl = v;
#pragma unroll
    for (int o = 1; o < 64; o <<= 1) {
        int nv = __shfl_up(incl, o, 64);
        if (t >= o) incl += nv;
    }
    if (t < SCAN_NB) blocksum[t] = incl - v;  // exclusive
}

__global__ void scan_phaseC(const int* __restrict__ deg, const int* __restrict__ blocksum,
                            int* __restrict__ rowptr, int* __restrict__ cursor) {
    __shared__ int woff[4];
    int t = threadIdx.x;
    int base = blockIdx.x * 1024 + t * 4;
    int d0 = 0, d1 = 0, d2 = 0, d3 = 0;
    if (base + 3 < NN) {
        int4 d = *reinterpret_cast<const int4*>(deg + base);
        d0 = d.x; d1 = d.y; d2 = d.z; d3 = d.w;
    } else {
        if (base + 0 < NN) d0 = deg[base + 0];
        if (base + 1 < NN) d1 = deg[base + 1];
        if (base + 2 < NN) d2 = deg[base + 2];
        if (base + 3 < NN) d3 = deg[base + 3];
    }
    int ts = d0 + d1 + d2 + d3;
    int lane = t & 63, w = t >> 6;
    int incl = ts;
#pragma unroll
    for (int o = 1; o < 64; o <<= 1) {
        int nv = __shfl_up(incl, o, 64);
        if (lane >= o) incl += nv;
    }
    if (lane == 63) woff[w] = incl;
    __syncthreads();
    if (t == 0) {
        int r = 0;
#pragma unroll
        for (int i = 0; i < 4; ++i) { int v = woff[i]; woff[i] = r; r += v; }
    }
    __syncthreads();
    int run = blocksum[blockIdx.x] + woff[w] + incl - ts;
    int r0 = run, r1 = r0 + d0, r2 = r1 + d1, r3 = r2 + d2;
    if (base + 3 < NN) {
        int4 rv; rv.x = r0; rv.y = r1; rv.z = r2; rv.w = r3;
        *reinterpret_cast<int4*>(rowptr + base) = rv;
        *reinterpret_cast<int4*>(cursor + base) = rv;
    } else {
        if (base + 0 < NN) { rowptr[base + 0] = r0; cursor[base + 0] = r0; }
        if (base + 1 < NN) { rowptr[base + 1] = r1; cursor[base + 1] = r1; }
        if (base + 2 < NN) { rowptr[base + 2] = r2; cursor[base + 2] = r2; }
    }
    if (blockIdx.x == 0 && t == 0) rowptr[NN] = NE;  // total degree is always E
}

// ---------------- bucket edges by dst: packed 8 B record ----------------
__global__ void fill_kernel(const int* __restrict__ src, const int* __restrict__ dst,
                            const float* __restrict__ attr, int* __restrict__ cursor,
                            int2* __restrict__ es, int E) {
    int e = blockIdx.x * blockDim.x + threadIdx.x;
    if (e >= E) return;
    int pos = atomicAdd(&cursor[dst[e]], 1);
    int2 rec;
    rec.x = src[e];
    rec.y = __float_as_int(attr[e]);
    es[pos] = rec;
}

// ---------------- matmul, thread = node, wave-uniform weight indices (SGPR weights) ----------------
// Yab (n,64,2) interleaved {a,b}; Z = x@R + B (n,64)
template<int CIN>
__global__ __launch_bounds__(256) void matmulAB_kernel(const float* __restrict__ x,
                               const float* __restrict__ W,   // (2, CIN, 64)
                               const float* __restrict__ R,   // (CIN, 64)
                               const float* __restrict__ Bb,  // (64)
                               float* __restrict__ Yab,
                               float* __restrict__ Z,
                               int n_nodes) {
    int n = blockIdx.x * blockDim.x + threadIdx.x;
    if (n >= n_nodes) return;
    float xr[CIN];
    const float4* xp = reinterpret_cast<const float4*>(x + (size_t)n * CIN);
#pragma unroll
    for (int i = 0; i < CIN / 4; ++i) {
        float4 v = xp[i];
        xr[4 * i + 0] = v.x; xr[4 * i + 1] = v.y; xr[4 * i + 2] = v.z; xr[4 * i + 3] = v.w;
    }
    const float* Wa = W;
    const float* Wb = W + CIN * 64;
    float* yout = Yab + (size_t)n * 128;
    // 4 tiles of 16 outputs; a and b together so stores are interleaved float4
#pragma unroll
    for (int t = 0; t < 4; ++t) {
        const int o0 = t * 16;
        float accA[16], accB[16];
#pragma unroll
        for (int j = 0; j < 16; ++j) { accA[j] = 0.f; accB[j] = 0.f; }
        for (int c = 0; c < CIN; ++c) {
            float xv = xr[c];
#pragma unroll
            for (int j = 0; j < 16; ++j) {
                accA[j] = fmaf(xv, Wa[c * 64 + o0 + j], accA[j]);   // uniform -> SGPR
                accB[j] = fmaf(xv, Wb[c * 64 + o0 + j], accB[j]);
            }
        }
#pragma unroll
        for (int j = 0; j < 16; j += 2) {
            float4 v; v.x = accA[j]; v.y = accB[j]; v.z = accA[j + 1]; v.w = accB[j + 1];
            *reinterpret_cast<float4*>(yout + 2 * (o0 + j)) = v;
        }
    }
    // Z in 2 tiles of 32
#pragma unroll
    for (int t = 0; t < 2; ++t) {
        const int o0 = t * 32;
        float acc[32];
#pragma unroll
        for (int j = 0; j < 32; ++j) acc[j] = 0.f;
        for (int c = 0; c < CIN; ++c) {
            float xv = xr[c];
#pragma unroll
            for (int j = 0; j < 32; ++j) acc[j] = fmaf(xv, R[c * 64 + o0 + j], acc[j]);
        }
#pragma unroll
        for (int j = 0; j < 32; j += 4) {
            float4 v;
            v.x = acc[j] + Bb[o0 + j];
            v.y = acc[j + 1] + Bb[o0 + j + 1];
            v.z = acc[j + 2] + Bb[o0 + j + 2];
            v.w = acc[j + 3] + Bb[o0 + j + 3];
            *reinterpret_cast<float4*>(Z + (size_t)n * 64 + o0 + j) = v;
        }
    }
}

// ---------------- layer-2 matmul, thread = node, COUT=7 ----------------
__global__ void matmul7_kernel(const float* __restrict__ x,   // (n,64)
                               const float* __restrict__ W,   // (2,64,7)
                               const float* __restrict__ R,   // (64,7)
                               const float* __restrict__ Bb,  // (7)
                               float* __restrict__ Yab,       // (n,7,2)
                               float* __restrict__ Z,         // (n,7)
                               int n_nodes) {
    int n = blockIdx.x * blockDim.x + threadIdx.x;
    if (n >= n_nodes) return;
    float xr[64];
    const float4* xp = reinterpret_cast<const float4*>(x + (size_t)n * 64);
#pragma unroll
    for (int i = 0; i < 16; ++i) {
        float4 v = xp[i];
        xr[4 * i + 0] = v.x; xr[4 * i + 1] = v.y; xr[4 * i + 2] = v.z; xr[4 * i + 3] = v.w;
    }
    float accA[7], accB[7], accZ[7];
#pragma unroll
    for (int j = 0; j < 7; ++j) { accA[j] = 0.f; accB[j] = 0.f; accZ[j] = 0.f; }
    for (int c = 0; c < 64; ++c) {
        float xv = xr[c];
#pragma unroll
        for (int j = 0; j < 7; ++j) {
            accA[j] = fmaf(xv, W[c * 7 + j], accA[j]);
            accB[j] = fmaf(xv, W[448 + c * 7 + j], accB[j]);
            accZ[j] = fmaf(xv, R[c * 7 + j], accZ[j]);
        }
    }
    float* yout = Yab + (size_t)n * 14;
#pragma unroll
    for (int j = 0; j < 7; ++j) {
        float2 v; v.x = accA[j]; v.y = accB[j];
        *reinterpret_cast<float2*>(yout + 2 * j) = v;
        Z[(size_t)n * 7 + j] = accZ[j] + Bb[j];
    }
}

// ---------------- gather (H=64) + BN + ELU fused: one wave per node, lane = channel ----------------
__global__ void gather64_kernel(const int* __restrict__ rowptr,
                                const int2* __restrict__ es,
                                const float* __restrict__ Yab,
                                const float* __restrict__ Z,
                                const float* __restrict__ G, const float* __restrict__ BE,
                                const float* __restrict__ RM, const float* __restrict__ RV,
                                float* __restrict__ h, int n_nodes) {
    int n = (blockIdx.x * blockDim.x + threadIdx.x) >> 6;
    int lane = threadIdx.x & 63;
    if (n >= n_nodes) return;
    int beg = rowptr[n], end = rowptr[n + 1];
    float acc0 = 0.f, acc1 = 0.f;
    int i = beg;
    for (; i + 1 < end; i += 2) {
        int2 e0 = es[i];
        int2 e1 = es[i + 1];
        float u0 = __int_as_float(e0.y);
        float u1 = __int_as_float(e1.y);
        float2 ab0 = *reinterpret_cast<const float2*>(Yab + (size_t)e0.x * 128 + 2 * lane);
        float2 ab1 = *reinterpret_cast<const float2*>(Yab + (size_t)e1.x * 128 + 2 * lane);
        acc0 += (1.f - u0) * ab0.x + u0 * ab0.y;
        acc1 += (1.f - u1) * ab1.x + u1 * ab1.y;
    }
    if (i < end) {
        int2 e0 = es[i];
        float u0 = __int_as_float(e0.y);
        float2 ab0 = *reinterpret_cast<const float2*>(Yab + (size_t)e0.x * 128 + 2 * lane);
        acc0 += (1.f - u0) * ab0.x + u0 * ab0.y;
    }
    float acc = acc0 + acc1;
    float degv = (float)(end - beg);
    if (degv < 1.f) degv = 1.f;
    float v = acc / degv + Z[n * 64 + lane];
    v = (v - RM[lane]) * rsqrtf(RV[lane] + EPSV) * G[lane] + BE[lane];
    h[n * 64 + lane] = v > 0.f ? v : expm1f(v);
}

// ---------------- gather (C=7) + log_softmax fused: 8 lanes per node ----------------
__global__ void gather7_final_kernel(const int* __restrict__ rowptr,
                                     const int2* __restrict__ es,
                                     const float* __restrict__ Yab,  // (n,7,2)
                                     const float* __restrict__ Z,
                                     float* __restrict__ out, int n_nodes) {
    int t = blockIdx.x * blockDim.x + threadIdx.x;
    int n = t >> 3;
    int c = t & 7;
    if (n >= n_nodes) return;
    int beg = rowptr[n], end = rowptr[n + 1];
    float acc = 0.f;
    if (c < 7) {
        for (int i = beg; i < end; ++i) {
            int2 e0 = es[i];
            float u = __int_as_float(e0.y);
            float2 ab = *reinterpret_cast<const float2*>(Yab + (size_t)e0.x * 14 + 2 * c);
            acc += (1.f - u) * ab.x + u * ab.y;
        }
    }
    float degv = (float)(end - beg);
    if (degv < 1.f) degv = 1.f;
    float v = (c < 7) ? (acc / degv + Z[n * 7 + c]) : -1e30f;
    float m = v;
#pragma unroll
    for (int o = 1; o < 8; o <<= 1) m = fmaxf(m, __shfl_xor(m, o, 8));
    float ex = (c < 7) ? expf(v - m) : 0.f;
    float ssum = ex;
#pragma unroll
    for (int o = 1; o < 8; o <<= 1) ssum += __shfl_xor(ssum, o, 8);
    if (c < 7) out[n * 7 + c] = v - m - logf(ssum);
}

extern "C" void kernel_launch(void* const* d_in, const int* in_sizes, int n_in,
                              void* d_out, int out_size, void* d_ws, size_t ws_size,
                              hipStream_t stream) {
    const float* x    = (const float*)d_in[0];
    const int*   ei   = (const int*)d_in[1];
    const float* attr = (const float*)d_in[2];
    const float* W0 = (const float*)d_in[3];
    const float* R0 = (const float*)d_in[4];
    const float* B0 = (const float*)d_in[5];
    const float* W1 = (const float*)d_in[6];
    const float* R1 = (const float*)d_in[7];
    const float* B1 = (const float*)d_in[8];
    const float* W2 = (const float*)d_in[9];
    const float* R2 = (const float*)d_in[10];
    const float* B2 = (const float*)d_in[11];
    const float* G0  = (const float*)d_in[12];
    const float* BE0 = (const float*)d_in[13];
    const float* RM0 = (const float*)d_in[14];
    const float* RV0 = (const float*)d_in[15];
    const float* G1  = (const float*)d_in[16];
    const float* BE1 = (const float*)d_in[17];
    const float* RM1 = (const float*)d_in[18];
    const float* RV1 = (const float*)d_in[19];

    const int* src = ei;
    const int* dst = ei + NE;
    float* out = (float*)d_out;

    // workspace layout
    char* ws = (char*)d_ws;
    size_t off = 0;
    auto alloc = [&](size_t bytes) { char* p = ws + off; off += (bytes + 255) & ~size_t(255); return p; };
    int*   deg      = (int*)  alloc(NN * sizeof(int));
    int*   rowptr   = (int*)  alloc((NN + 1) * sizeof(int));
    int*   cursor   = (int*)  alloc(NN * sizeof(int));
    int*   blocksum = (int*)  alloc(SCAN_NB * sizeof(int));
    int2*  es       = (int2*) alloc((size_t)NE * sizeof(int2));
    float* Yab      = (float*)alloc((size_t)NN * 128 * sizeof(float));
    float* Z        = (float*)alloc((size_t)NN * 64 * sizeof(float));
    float* h        = (float*)alloc((size_t)NN * 64 * sizeof(float));

    const int B = 256;
    const int gE    = (NE + B - 1) / B;
    const int gN64  = (NN * 64 + B - 1) / B;
    const int gN    = (NN + B - 1) / B;
    const int gN8   = (NN * 8 + B - 1) / B;

    // ---- CSR build (once, reused by all 3 layers) ----
    hipMemsetAsync(deg, 0, NN * sizeof(int), stream);
    deg_kernel<<<gE, B, 0, stream>>>(dst, deg, NE);
    scan_phaseA<<<SCAN_NB, 256, 0, stream>>>(deg, blocksum);
    scan_phaseB<<<1, 64, 0, stream>>>(blocksum);
    scan_phaseC<<<SCAN_NB, 256, 0, stream>>>(deg, blocksum, rowptr, cursor);
    fill_kernel<<<gE, B, 0, stream>>>(src, dst, attr, cursor, es, NE);

    // ---- layer 0: F_IN=32 -> H=64 ----
    matmulAB_kernel<32><<<gN, B, 0, stream>>>(x, W0, R0, B0, Yab, Z, NN);
    gather64_kernel<<<gN64, B, 0, stream>>>(rowptr, es, Yab, Z, G0, BE0, RM0, RV0, h, NN);

    // ---- layer 1: H=64 -> H=64 ----
    matmulAB_kernel<64><<<gN, B, 0, stream>>>(h, W1, R1, B1, Yab, Z, NN);
    gather64_kernel<<<gN64, B, 0, stream>>>(rowptr, es, Yab, Z, G1, BE1, RM1, RV1, h, NN);

    // ---- layer 2: H=64 -> C=7, then log_softmax ----
    matmul7_kernel<<<gN, B, 0, stream>>>(h, W2, R2, B2, Yab, Z, NN);
    gather7_final_kernel<<<gN8, B, 0, stream>>>(rowptr, es, Yab, Z, out, NN);
}

// Round 6
// 431.219 us; speedup vs baseline: 1.2413x; 1.2413x over previous
//
#include <hip/hip_runtime.h>
#include <math.h>

#define NN 50000
#define NE 800000
#define EPSV 1e-5f
#define SCAN_NB 49   // ceil(NN / 1024)

// ---------------- degree count ----------------
__global__ void deg_kernel(const int* __restrict__ dst, int* __restrict__ deg, int E) {
    int e = blockIdx.x * blockDim.x + threadIdx.x;
    if (e < E) atomicAdd(&deg[dst[e]], 1);
}

// ---------------- 3-phase grid-wide exclusive scan of deg -> rowptr, cursor ----------------
__global__ void scan_phaseA(const int* __restrict__ deg, int* __restrict__ blocksum) {
    __shared__ int wsums[4];
    int t = threadIdx.x;
    int base = blockIdx.x * 1024 + t * 4;
    int s = 0;
    if (base + 3 < NN) {
        int4 d = *reinterpret_cast<const int4*>(deg + base);
        s = d.x + d.y + d.z + d.w;
    } else {
        for (int j = 0; j < 4; ++j) if (base + j < NN) s += deg[base + j];
    }
#pragma unroll
    for (int o = 1; o < 64; o <<= 1) s += __shfl_xor(s, o, 64);
    if ((t & 63) == 0) wsums[t >> 6] = s;
    __syncthreads();
    if (t == 0) blocksum[blockIdx.x] = wsums[0] + wsums[1] + wsums[2] + wsums[3];
}

__global__ void scan_phaseB(int* __restrict__ blocksum) {
    int t = threadIdx.x;  // 64 threads
    int v = (t < SCAN_NB) ? blocksum[t] : 0;
    int incl = v;
#pragma unroll
    for (int o = 1; o < 64; o <<= 1) {
        int nv = __shfl_up(incl, o, 64);
        if (t >= o) incl += nv;
    }
    if (t < SCAN_NB) blocksum[t] = incl - v;  // exclusive
}

__global__ void scan_phaseC(const int* __restrict__ deg, const int* __restrict__ blocksum,
                            int* __restrict__ rowptr, int* __restrict__ cursor) {
    __shared__ int woff[4];
    int t = threadIdx.x;
    int base = blockIdx.x * 1024 + t * 4;
    int d0 = 0, d1 = 0, d2 = 0, d3 = 0;
    if (base + 3 < NN) {
        int4 d = *reinterpret_cast<const int4*>(deg + base);
        d0 = d.x; d1 = d.y; d2 = d.z; d3 = d.w;
    } else {
        if (base + 0 < NN) d0 = deg[base + 0];
        if (base + 1 < NN) d1 = deg[base + 1];
        if (base + 2 < NN) d2 = deg[base + 2];
        if (base + 3 < NN) d3 = deg[base + 3];
    }
    int ts = d0 + d1 + d2 + d3;
    int lane = t & 63, w = t >> 6;
    int incl = ts;
#pragma unroll
    for (int o = 1; o < 64; o <<= 1) {
        int nv = __shfl_up(incl, o, 64);
        if (lane >= o) incl += nv;
    }
    if (lane == 63) woff[w] = incl;
    __syncthreads();
    if (t == 0) {
        int r = 0;
#pragma unroll
        for (int i = 0; i < 4; ++i) { int v = woff[i]; woff[i] = r; r += v; }
    }
    __syncthreads();
    int run = blocksum[blockIdx.x] + woff[w] + incl - ts;
    int r0 = run, r1 = r0 + d0, r2 = r1 + d1, r3 = r2 + d2;
    if (base + 3 < NN) {
        int4 rv; rv.x = r0; rv.y = r1; rv.z = r2; rv.w = r3;
        *reinterpret_cast<int4*>(rowptr + base) = rv;
        *reinterpret_cast<int4*>(cursor + base) = rv;
    } else {
        if (base + 0 < NN) { rowptr[base + 0] = r0; cursor[base + 0] = r0; }
        if (base + 1 < NN) { rowptr[base + 1] = r1; cursor[base + 1] = r1; }
        if (base + 2 < NN) { rowptr[base + 2] = r2; cursor[base + 2] = r2; }
    }
    if (blockIdx.x == 0 && t == 0) rowptr[NN] = NE;  // total degree is always E
}

// ---------------- bucket edges by dst: packed 8 B record ----------------
__global__ void fill_kernel(const int* __restrict__ src, const int* __restrict__ dst,
                            const float* __restrict__ attr, int* __restrict__ cursor,
                            int2* __restrict__ es, int E) {
    int e = blockIdx.x * blockDim.x + threadIdx.x;
    if (e >= E) return;
    int pos = atomicAdd(&cursor[dst[e]], 1);
    int2 rec;
    rec.x = src[e];
    rec.y = __float_as_int(attr[e]);
    es[pos] = rec;
}

// ---------------- matmul: thread = node, blockIdx.y = output quarter (SGPR weights) ----------------
// Yab (n,64,2) interleaved {a,b}; Z = x@R + B (n,64)
template<int CIN>
__global__ __launch_bounds__(256) void matmulAB_kernel(const float* __restrict__ x,
                               const float* __restrict__ W,   // (2, CIN, 64)
                               const float* __restrict__ R,   // (CIN, 64)
                               const float* __restrict__ Bb,  // (64)
                               float* __restrict__ Yab,
                               float* __restrict__ Z,
                               int n_nodes) {
    int n = blockIdx.x * blockDim.x + threadIdx.x;
    if (n >= n_nodes) return;
    const int o0 = blockIdx.y * 16;  // block-uniform output quarter
    float xr[CIN];
    const float4* xp = reinterpret_cast<const float4*>(x + (size_t)n * CIN);
#pragma unroll
    for (int i = 0; i < CIN / 4; ++i) {
        float4 v = xp[i];
        xr[4 * i + 0] = v.x; xr[4 * i + 1] = v.y; xr[4 * i + 2] = v.z; xr[4 * i + 3] = v.w;
    }
    const float* Wa = W + o0;
    const float* Wb = W + CIN * 64 + o0;
    const float* Rq = R + o0;
    float accA[16], accB[16], accZ[16];
#pragma unroll
    for (int j = 0; j < 16; ++j) { accA[j] = 0.f; accB[j] = 0.f; accZ[j] = 0.f; }
    for (int c = 0; c < CIN; ++c) {
        float xv = xr[c];
#pragma unroll
        for (int j = 0; j < 16; ++j) {
            accA[j] = fmaf(xv, Wa[c * 64 + j], accA[j]);  // uniform idx -> s_load_dwordx16
            accB[j] = fmaf(xv, Wb[c * 64 + j], accB[j]);
            accZ[j] = fmaf(xv, Rq[c * 64 + j], accZ[j]);
        }
    }
    float* yout = Yab + (size_t)n * 128 + 2 * o0;
#pragma unroll
    for (int j = 0; j < 16; j += 2) {
        float4 v; v.x = accA[j]; v.y = accB[j]; v.z = accA[j + 1]; v.w = accB[j + 1];
        *reinterpret_cast<float4*>(yout + 2 * j) = v;
    }
    float* zout = Z + (size_t)n * 64 + o0;
#pragma unroll
    for (int j = 0; j < 16; j += 4) {
        float4 v;
        v.x = accZ[j]     + Bb[o0 + j];
        v.y = accZ[j + 1] + Bb[o0 + j + 1];
        v.z = accZ[j + 2] + Bb[o0 + j + 2];
        v.w = accZ[j + 3] + Bb[o0 + j + 3];
        *reinterpret_cast<float4*>(zout + j) = v;
    }
}

// ---------------- layer-2 matmul: thread = node, blockIdx.y = {a,b,z} part ----------------
__global__ __launch_bounds__(256) void matmul7_kernel(const float* __restrict__ x,   // (n,64)
                               const float* __restrict__ W,   // (2,64,7)
                               const float* __restrict__ R,   // (64,7)
                               const float* __restrict__ Bb,  // (7)
                               float* __restrict__ Yab,       // (n,7,2)
                               float* __restrict__ Z,         // (n,7)
                               int n_nodes) {
    int n = blockIdx.x * blockDim.x + threadIdx.x;
    if (n >= n_nodes) return;
    const int part = blockIdx.y;  // 0: a, 1: b, 2: z
    const float* M = (part == 0) ? W : (part == 1) ? (W + 448) : R;
    float xr[64];
    const float4* xp = reinterpret_cast<const float4*>(x + (size_t)n * 64);
#pragma unroll
    for (int i = 0; i < 16; ++i) {
        float4 v = xp[i];
        xr[4 * i + 0] = v.x; xr[4 * i + 1] = v.y; xr[4 * i + 2] = v.z; xr[4 * i + 3] = v.w;
    }
    float acc[7];
#pragma unroll
    for (int j = 0; j < 7; ++j) acc[j] = 0.f;
    for (int c = 0; c < 64; ++c) {
        float xv = xr[c];
#pragma unroll
        for (int j = 0; j < 7; ++j) acc[j] = fmaf(xv, M[c * 7 + j], acc[j]);
    }
    if (part == 0) {
#pragma unroll
        for (int j = 0; j < 7; ++j) Yab[(size_t)n * 14 + 2 * j] = acc[j];
    } else if (part == 1) {
#pragma unroll
        for (int j = 0; j < 7; ++j) Yab[(size_t)n * 14 + 2 * j + 1] = acc[j];
    } else {
#pragma unroll
        for (int j = 0; j < 7; ++j) Z[(size_t)n * 7 + j] = acc[j] + Bb[j];
    }
}

// ---------------- gather (H=64) + BN + ELU fused: one wave per node, lane = channel ----------------
__global__ void gather64_kernel(const int* __restrict__ rowptr,
                                const int2* __restrict__ es,
                                const float* __restrict__ Yab,
                                const float* __restrict__ Z,
                                const float* __restrict__ G, const float* __restrict__ BE,
                                const float* __restrict__ RM, const float* __restrict__ RV,
                                float* __restrict__ h, int n_nodes) {
    int n = (blockIdx.x * blockDim.x + threadIdx.x) >> 6;
    int lane = threadIdx.x & 63;
    if (n >= n_nodes) return;
    int beg = rowptr[n], end = rowptr[n + 1];
    float acc0 = 0.f, acc1 = 0.f;
    int i = beg;
    for (; i + 1 < end; i += 2) {
        int2 e0 = es[i];
        int2 e1 = es[i + 1];
        float u0 = __int_as_float(e0.y);
        float u1 = __int_as_float(e1.y);
        float2 ab0 = *reinterpret_cast<const float2*>(Yab + (size_t)e0.x * 128 + 2 * lane);
        float2 ab1 = *reinterpret_cast<const float2*>(Yab + (size_t)e1.x * 128 + 2 * lane);
        acc0 += (1.f - u0) * ab0.x + u0 * ab0.y;
        acc1 += (1.f - u1) * ab1.x + u1 * ab1.y;
    }
    if (i < end) {
        int2 e0 = es[i];
        float u0 = __int_as_float(e0.y);
        float2 ab0 = *reinterpret_cast<const float2*>(Yab + (size_t)e0.x * 128 + 2 * lane);
        acc0 += (1.f - u0) * ab0.x + u0 * ab0.y;
    }
    float acc = acc0 + acc1;
    float degv = (float)(end - beg);
    if (degv < 1.f) degv = 1.f;
    float v = acc / degv + Z[n * 64 + lane];
    v = (v - RM[lane]) * rsqrtf(RV[lane] + EPSV) * G[lane] + BE[lane];
    h[n * 64 + lane] = v > 0.f ? v : expm1f(v);
}

// ---------------- gather (C=7) + log_softmax fused: 8 lanes per node ----------------
__global__ void gather7_final_kernel(const int* __restrict__ rowptr,
                                     const int2* __restrict__ es,
                                     const float* __restrict__ Yab,  // (n,7,2)
                                     const float* __restrict__ Z,
                                     float* __restrict__ out, int n_nodes) {
    int t = blockIdx.x * blockDim.x + threadIdx.x;
    int n = t >> 3;
    int c = t & 7;
    if (n >= n_nodes) return;
    int beg = rowptr[n], end = rowptr[n + 1];
    float acc = 0.f;
    if (c < 7) {
        for (int i = beg; i < end; ++i) {
            int2 e0 = es[i];
            float u = __int_as_float(e0.y);
            float2 ab = *reinterpret_cast<const float2*>(Yab + (size_t)e0.x * 14 + 2 * c);
            acc += (1.f - u) * ab.x + u * ab.y;
        }
    }
    float degv = (float)(end - beg);
    if (degv < 1.f) degv = 1.f;
    float v = (c < 7) ? (acc / degv + Z[n * 7 + c]) : -1e30f;
    float m = v;
#pragma unroll
    for (int o = 1; o < 8; o <<= 1) m = fmaxf(m, __shfl_xor(m, o, 8));
    float ex = (c < 7) ? expf(v - m) : 0.f;
    float ssum = ex;
#pragma unroll
    for (int o = 1; o < 8; o <<= 1) ssum += __shfl_xor(ssum, o, 8);
    if (c < 7) out[n * 7 + c] = v - m - logf(ssum);
}

extern "C" void kernel_launch(void* const* d_in, const int* in_sizes, int n_in,
                              void* d_out, int out_size, void* d_ws, size_t ws_size,
                              hipStream_t stream) {
    const float* x    = (const float*)d_in[0];
    const int*   ei   = (const int*)d_in[1];
    const float* attr = (const float*)d_in[2];
    const float* W0 = (const float*)d_in[3];
    const float* R0 = (const float*)d_in[4];
    const float* B0 = (const float*)d_in[5];
    const float* W1 = (const float*)d_in[6];
    const float* R1 = (const float*)d_in[7];
    const float* B1 = (const float*)d_in[8];
    const float* W2 = (const float*)d_in[9];
    const float* R2 = (const float*)d_in[10];
    const float* B2 = (const float*)d_in[11];
    const float* G0  = (const float*)d_in[12];
    const float* BE0 = (const float*)d_in[13];
    const float* RM0 = (const float*)d_in[14];
    const float* RV0 = (const float*)d_in[15];
    const float* G1  = (const float*)d_in[16];
    const float* BE1 = (const float*)d_in[17];
    const float* RM1 = (const float*)d_in[18];
    const float* RV1 = (const float*)d_in[19];

    const int* src = ei;
    const int* dst = ei + NE;
    float* out = (float*)d_out;

    // workspace layout
    char* ws = (char*)d_ws;
    size_t off = 0;
    auto alloc = [&](size_t bytes) { char* p = ws + off; off += (bytes + 255) & ~size_t(255); return p; };
    int*   deg      = (int*)  alloc(NN * sizeof(int));
    int*   rowptr   = (int*)  alloc((NN + 1) * sizeof(int));
    int*   cursor   = (int*)  alloc(NN * sizeof(int));
    int*   blocksum = (int*)  alloc(SCAN_NB * sizeof(int));
    int2*  es       = (int2*) alloc((size_t)NE * sizeof(int2));
    float* Yab      = (float*)alloc((size_t)NN * 128 * sizeof(float));
    float* Z        = (float*)alloc((size_t)NN * 64 * sizeof(float));
    float* h        = (float*)alloc((size_t)NN * 64 * sizeof(float));

    const int B = 256;
    const int gE    = (NE + B - 1) / B;
    const int gN64  = (NN * 64 + B - 1) / B;
    const int gN    = (NN + B - 1) / B;
    const int gN8   = (NN * 8 + B - 1) / B;

    // ---- CSR build (once, reused by all 3 layers) ----
    hipMemsetAsync(deg, 0, NN * sizeof(int), stream);
    deg_kernel<<<gE, B, 0, stream>>>(dst, deg, NE);
    scan_phaseA<<<SCAN_NB, 256, 0, stream>>>(deg, blocksum);
    scan_phaseB<<<1, 64, 0, stream>>>(blocksum);
    scan_phaseC<<<SCAN_NB, 256, 0, stream>>>(deg, blocksum, rowptr, cursor);
    fill_kernel<<<gE, B, 0, stream>>>(src, dst, attr, cursor, es, NE);

    // ---- layer 0: F_IN=32 -> H=64 ----
    matmulAB_kernel<32><<<dim3(gN, 4), B, 0, stream>>>(x, W0, R0, B0, Yab, Z, NN);
    gather64_kernel<<<gN64, B, 0, stream>>>(rowptr, es, Yab, Z, G0, BE0, RM0, RV0, h, NN);

    // ---- layer 1: H=64 -> H=64 ----
    matmulAB_kernel<64><<<dim3(gN, 4), B, 0, stream>>>(h, W1, R1, B1, Yab, Z, NN);
    gather64_kernel<<<gN64, B, 0, stream>>>(rowptr, es, Yab, Z, G1, BE1, RM1, RV1, h, NN);

    // ---- layer 2: H=64 -> C=7, then log_softmax ----
    matmul7_kernel<<<dim3(gN, 3), B, 0, stream>>>(h, W2, R2, B2, Yab, Z, NN);
    gather7_final_kernel<<<gN8, B, 0, stream>>>(rowptr, es, Yab, Z, out, NN);
}

// Round 7
// 409.276 us; speedup vs baseline: 1.3079x; 1.0536x over previous
//
#include <hip/hip_runtime.h>
#include <hip/hip_fp16.h>
#include <math.h>

#define NN 50000
#define NE 800000
#define EPSV 1e-5f
#define SCAN_NB 49   // ceil(NN / 1024)

// ---------------- degree count ----------------
__global__ void deg_kernel(const int* __restrict__ dst, int* __restrict__ deg, int E) {
    int e = blockIdx.x * blockDim.x + threadIdx.x;
    if (e < E) atomicAdd(&deg[dst[e]], 1);
}

// ---------------- 3-phase grid-wide exclusive scan of deg -> rowptr, cursor ----------------
__global__ void scan_phaseA(const int* __restrict__ deg, int* __restrict__ blocksum) {
    __shared__ int wsums[4];
    int t = threadIdx.x;
    int base = blockIdx.x * 1024 + t * 4;
    int s = 0;
    if (base + 3 < NN) {
        int4 d = *reinterpret_cast<const int4*>(deg + base);
        s = d.x + d.y + d.z + d.w;
    } else {
        for (int j = 0; j < 4; ++j) if (base + j < NN) s += deg[base + j];
    }
#pragma unroll
    for (int o = 1; o < 64; o <<= 1) s += __shfl_xor(s, o, 64);
    if ((t & 63) == 0) wsums[t >> 6] = s;
    __syncthreads();
    if (t == 0) blocksum[blockIdx.x] = wsums[0] + wsums[1] + wsums[2] + wsums[3];
}

__global__ void scan_phaseB(int* __restrict__ blocksum) {
    int t = threadIdx.x;  // 64 threads
    int v = (t < SCAN_NB) ? blocksum[t] : 0;
    int incl = v;
#pragma unroll
    for (int o = 1; o < 64; o <<= 1) {
        int nv = __shfl_up(incl, o, 64);
        if (t >= o) incl += nv;
    }
    if (t < SCAN_NB) blocksum[t] = incl - v;  // exclusive
}

__global__ void scan_phaseC(const int* __restrict__ deg, const int* __restrict__ blocksum,
                            int* __restrict__ rowptr, int* __restrict__ cursor) {
    __shared__ int woff[4];
    int t = threadIdx.x;
    int base = blockIdx.x * 1024 + t * 4;
    int d0 = 0, d1 = 0, d2 = 0, d3 = 0;
    if (base + 3 < NN) {
        int4 d = *reinterpret_cast<const int4*>(deg + base);
        d0 = d.x; d1 = d.y; d2 = d.z; d3 = d.w;
    } else {
        if (base + 0 < NN) d0 = deg[base + 0];
        if (base + 1 < NN) d1 = deg[base + 1];
        if (base + 2 < NN) d2 = deg[base + 2];
        if (base + 3 < NN) d3 = deg[base + 3];
    }
    int ts = d0 + d1 + d2 + d3;
    int lane = t & 63, w = t >> 6;
    int incl = ts;
#pragma unroll
    for (int o = 1; o < 64; o <<= 1) {
        int nv = __shfl_up(incl, o, 64);
        if (lane >= o) incl += nv;
    }
    if (lane == 63) woff[w] = incl;
    __syncthreads();
    if (t == 0) {
        int r = 0;
#pragma unroll
        for (int i = 0; i < 4; ++i) { int v = woff[i]; woff[i] = r; r += v; }
    }
    __syncthreads();
    int run = blocksum[blockIdx.x] + woff[w] + incl - ts;
    int r0 = run, r1 = r0 + d0, r2 = r1 + d1, r3 = r2 + d2;
    if (base + 3 < NN) {
        int4 rv; rv.x = r0; rv.y = r1; rv.z = r2; rv.w = r3;
        *reinterpret_cast<int4*>(rowptr + base) = rv;
        *reinterpret_cast<int4*>(cursor + base) = rv;
    } else {
        if (base + 0 < NN) { rowptr[base + 0] = r0; cursor[base + 0] = r0; }
        if (base + 1 < NN) { rowptr[base + 1] = r1; cursor[base + 1] = r1; }
        if (base + 2 < NN) { rowptr[base + 2] = r2; cursor[base + 2] = r2; }
    }
    if (blockIdx.x == 0 && t == 0) rowptr[NN] = NE;  // total degree is always E
}

// ---------------- bucket edges by dst: packed 8 B record ----------------
__global__ void fill_kernel(const int* __restrict__ src, const int* __restrict__ dst,
                            const float* __restrict__ attr, int* __restrict__ cursor,
                            int2* __restrict__ es, int E) {
    int e = blockIdx.x * blockDim.x + threadIdx.x;
    if (e >= E) return;
    int pos = atomicAdd(&cursor[dst[e]], 1);
    int2 rec;
    rec.x = src[e];
    rec.y = __float_as_int(attr[e]);
    es[pos] = rec;
}

// ---------------- matmul: thread = node, blockIdx.y = 8-output chunk (SGPR weights) ----------------
// YabH (n,64) half2 {a,b}; Z = x@R + B (n,64) fp32
template<int CIN>
__global__ __launch_bounds__(256) void matmulAB_kernel(const float* __restrict__ x,
                               const float* __restrict__ W,   // (2, CIN, 64)
                               const float* __restrict__ R,   // (CIN, 64)
                               const float* __restrict__ Bb,  // (64)
                               __half2* __restrict__ YabH,
                               float* __restrict__ Z,
                               int n_nodes) {
    int n = blockIdx.x * blockDim.x + threadIdx.x;
    if (n >= n_nodes) return;
    const int o0 = blockIdx.y * 8;  // block-uniform 8-output chunk
    const float* Wa = W + o0;
    const float* Wb = W + CIN * 64 + o0;
    const float* Rq = R + o0;
    const float* xr = x + (size_t)n * CIN;
    float accA[8], accB[8], accZ[8];
#pragma unroll
    for (int j = 0; j < 8; ++j) { accA[j] = 0.f; accB[j] = 0.f; accZ[j] = 0.f; }
#pragma unroll 2
    for (int c0 = 0; c0 < CIN; c0 += 4) {
        float4 xv4 = *reinterpret_cast<const float4*>(xr + c0);
        float xv[4] = { xv4.x, xv4.y, xv4.z, xv4.w };
#pragma unroll
        for (int cc = 0; cc < 4; ++cc) {
            float xv_ = xv[cc];
            int c = c0 + cc;
#pragma unroll
            for (int j = 0; j < 8; ++j) {
                accA[j] = fmaf(xv_, Wa[c * 64 + j], accA[j]);  // uniform idx -> s_load
                accB[j] = fmaf(xv_, Wb[c * 64 + j], accB[j]);
                accZ[j] = fmaf(xv_, Rq[c * 64 + j], accZ[j]);
            }
        }
    }
    union { __half2 h2[8]; uint4 u4[2]; } pk;
#pragma unroll
    for (int j = 0; j < 8; ++j) pk.h2[j] = __floats2half2_rn(accA[j], accB[j]);
    uint4* yo = reinterpret_cast<uint4*>(YabH + (size_t)n * 64 + o0);  // 32 B, 16 B-aligned
    yo[0] = pk.u4[0];
    yo[1] = pk.u4[1];
    float* zout = Z + (size_t)n * 64 + o0;
#pragma unroll
    for (int j = 0; j < 8; j += 4) {
        float4 v;
        v.x = accZ[j]     + Bb[o0 + j];
        v.y = accZ[j + 1] + Bb[o0 + j + 1];
        v.z = accZ[j + 2] + Bb[o0 + j + 2];
        v.w = accZ[j + 3] + Bb[o0 + j + 3];
        *reinterpret_cast<float4*>(zout + j) = v;
    }
}

// ---------------- layer-2 matmul: thread = node, blockIdx.y = {a,b,z} part ----------------
__global__ __launch_bounds__(256) void matmul7_kernel(const float* __restrict__ x,   // (n,64)
                               const float* __restrict__ W,   // (2,64,7)
                               const float* __restrict__ R,   // (64,7)
                               const float* __restrict__ Bb,  // (7)
                               float* __restrict__ Yab7,      // (n,7,2)
                               float* __restrict__ Z,         // (n,7)
                               int n_nodes) {
    int n = blockIdx.x * blockDim.x + threadIdx.x;
    if (n >= n_nodes) return;
    const int part = blockIdx.y;  // 0: a, 1: b, 2: z
    const float* M = (part == 0) ? W : (part == 1) ? (W + 448) : R;
    const float* xr = x + (size_t)n * 64;
    float acc[7];
#pragma unroll
    for (int j = 0; j < 7; ++j) acc[j] = 0.f;
#pragma unroll 2
    for (int c0 = 0; c0 < 64; c0 += 4) {
        float4 xv4 = *reinterpret_cast<const float4*>(xr + c0);
        float xv[4] = { xv4.x, xv4.y, xv4.z, xv4.w };
#pragma unroll
        for (int cc = 0; cc < 4; ++cc) {
            float xv_ = xv[cc];
            int c = c0 + cc;
#pragma unroll
            for (int j = 0; j < 7; ++j) acc[j] = fmaf(xv_, M[c * 7 + j], acc[j]);
        }
    }
    if (part == 0) {
#pragma unroll
        for (int j = 0; j < 7; ++j) Yab7[(size_t)n * 14 + 2 * j] = acc[j];
    } else if (part == 1) {
#pragma unroll
        for (int j = 0; j < 7; ++j) Yab7[(size_t)n * 14 + 2 * j + 1] = acc[j];
    } else {
#pragma unroll
        for (int j = 0; j < 7; ++j) Z[(size_t)n * 7 + j] = acc[j] + Bb[j];
    }
}

// ---------------- gather (H=64, fp16 Yab) + BN + ELU fused: one wave per node, lane = channel ----------------
__global__ void gather64_kernel(const int* __restrict__ rowptr,
                                const int2* __restrict__ es,
                                const __half2* __restrict__ YabH,
                                const float* __restrict__ Z,
                                const float* __restrict__ G, const float* __restrict__ BE,
                                const float* __restrict__ RM, const float* __restrict__ RV,
                                float* __restrict__ h, int n_nodes) {
    int n = (blockIdx.x * blockDim.x + threadIdx.x) >> 6;
    int lane = threadIdx.x & 63;
    if (n >= n_nodes) return;
    int beg = rowptr[n], end = rowptr[n + 1];
    float acc0 = 0.f, acc1 = 0.f;
    int i = beg;
    for (; i + 1 < end; i += 2) {
        int2 e0 = es[i];
        int2 e1 = es[i + 1];
        float u0 = __int_as_float(e0.y);
        float u1 = __int_as_float(e1.y);
        float2 ab0 = __half22float2(YabH[(size_t)e0.x * 64 + lane]);
        float2 ab1 = __half22float2(YabH[(size_t)e1.x * 64 + lane]);
        acc0 += (1.f - u0) * ab0.x + u0 * ab0.y;
        acc1 += (1.f - u1) * ab1.x + u1 * ab1.y;
    }
    if (i < end) {
        int2 e0 = es[i];
        float u0 = __int_as_float(e0.y);
        float2 ab0 = __half22float2(YabH[(size_t)e0.x * 64 + lane]);
        acc0 += (1.f - u0) * ab0.x + u0 * ab0.y;
    }
    float acc = acc0 + acc1;
    float degv = (float)(end - beg);
    if (degv < 1.f) degv = 1.f;
    float v = acc / degv + Z[n * 64 + lane];
    v = (v - RM[lane]) * rsqrtf(RV[lane] + EPSV) * G[lane] + BE[lane];
    h[n * 64 + lane] = v > 0.f ? v : expm1f(v);
}

// ---------------- gather (C=7) + log_softmax fused: 8 lanes per node ----------------
__global__ void gather7_final_kernel(const int* __restrict__ rowptr,
                                     const int2* __restrict__ es,
                                     const float* __restrict__ Yab7,  // (n,7,2)
                                     const float* __restrict__ Z,
                                     float* __restrict__ out, int n_nodes) {
    int t = blockIdx.x * blockDim.x + threadIdx.x;
    int n = t >> 3;
    int c = t & 7;
    if (n >= n_nodes) return;
    int beg = rowptr[n], end = rowptr[n + 1];
    float acc = 0.f;
    if (c < 7) {
        for (int i = beg; i < end; ++i) {
            int2 e0 = es[i];
            float u = __int_as_float(e0.y);
            float2 ab = *reinterpret_cast<const float2*>(Yab7 + (size_t)e0.x * 14 + 2 * c);
            acc += (1.f - u) * ab.x + u * ab.y;
        }
    }
    float degv = (float)(end - beg);
    if (degv < 1.f) degv = 1.f;
    float v = (c < 7) ? (acc / degv + Z[n * 7 + c]) : -1e30f;
    float m = v;
#pragma unroll
    for (int o = 1; o < 8; o <<= 1) m = fmaxf(m, __shfl_xor(m, o, 8));
    float ex = (c < 7) ? expf(v - m) : 0.f;
    float ssum = ex;
#pragma unroll
    for (int o = 1; o < 8; o <<= 1) ssum += __shfl_xor(ssum, o, 8);
    if (c < 7) out[n * 7 + c] = v - m - logf(ssum);
}

extern "C" void kernel_launch(void* const* d_in, const int* in_sizes, int n_in,
                              void* d_out, int out_size, void* d_ws, size_t ws_size,
                              hipStream_t stream) {
    const float* x    = (const float*)d_in[0];
    const int*   ei   = (const int*)d_in[1];
    const float* attr = (const float*)d_in[2];
    const float* W0 = (const float*)d_in[3];
    const float* R0 = (const float*)d_in[4];
    const float* B0 = (const float*)d_in[5];
    const float* W1 = (const float*)d_in[6];
    const float* R1 = (const float*)d_in[7];
    const float* B1 = (const float*)d_in[8];
    const float* W2 = (const float*)d_in[9];
    const float* R2 = (const float*)d_in[10];
    const float* B2 = (const float*)d_in[11];
    const float* G0  = (const float*)d_in[12];
    const float* BE0 = (const float*)d_in[13];
    const float* RM0 = (const float*)d_in[14];
    const float* RV0 = (const float*)d_in[15];
    const float* G1  = (const float*)d_in[16];
    const float* BE1 = (const float*)d_in[17];
    const float* RM1 = (const float*)d_in[18];
    const float* RV1 = (const float*)d_in[19];

    const int* src = ei;
    const int* dst = ei + NE;
    float* out = (float*)d_out;

    // workspace layout
    char* ws = (char*)d_ws;
    size_t off = 0;
    auto alloc = [&](size_t bytes) { char* p = ws + off; off += (bytes + 255) & ~size_t(255); return p; };
    int*     deg      = (int*)    alloc(NN * sizeof(int));
    int*     rowptr   = (int*)    alloc((NN + 1) * sizeof(int));
    int*     cursor   = (int*)    alloc(NN * sizeof(int));
    int*     blocksum = (int*)    alloc(SCAN_NB * sizeof(int));
    int2*    es       = (int2*)   alloc((size_t)NE * sizeof(int2));
    __half2* YabH     = (__half2*)alloc((size_t)NN * 64 * sizeof(__half2));
    float*   Yab7     = (float*)  alloc((size_t)NN * 14 * sizeof(float));
    float*   Z        = (float*)  alloc((size_t)NN * 64 * sizeof(float));
    float*   h        = (float*)  alloc((size_t)NN * 64 * sizeof(float));

    const int B = 256;
    const int gE    = (NE + B - 1) / B;
    const int gN64  = (NN * 64 + B - 1) / B;
    const int gN    = (NN + B - 1) / B;
    const int gN8   = (NN * 8 + B - 1) / B;

    // ---- CSR build (once, reused by all 3 layers) ----
    hipMemsetAsync(deg, 0, NN * sizeof(int), stream);
    deg_kernel<<<gE, B, 0, stream>>>(dst, deg, NE);
    scan_phaseA<<<SCAN_NB, 256, 0, stream>>>(deg, blocksum);
    scan_phaseB<<<1, 64, 0, stream>>>(blocksum);
    scan_phaseC<<<SCAN_NB, 256, 0, stream>>>(deg, blocksum, rowptr, cursor);
    fill_kernel<<<gE, B, 0, stream>>>(src, dst, attr, cursor, es, NE);

    // ---- layer 0: F_IN=32 -> H=64 ----
    matmulAB_kernel<32><<<dim3(gN, 8), B, 0, stream>>>(x, W0, R0, B0, YabH, Z, NN);
    gather64_kernel<<<gN64, B, 0, stream>>>(rowptr, es, YabH, Z, G0, BE0, RM0, RV0, h, NN);

    // ---- layer 1: H=64 -> H=64 ----
    matmulAB_kernel<64><<<dim3(gN, 8), B, 0, stream>>>(h, W1, R1, B1, YabH, Z, NN);
    gather64_kernel<<<gN64, B, 0, stream>>>(rowptr, es, YabH, Z, G1, BE1, RM1, RV1, h, NN);

    // ---- layer 2: H=64 -> C=7, then log_softmax ----
    matmul7_kernel<<<dim3(gN, 3), B, 0, stream>>>(h, W2, R2, B2, Yab7, Z, NN);
    gather7_final_kernel<<<gN8, B, 0, stream>>>(rowptr, es, Yab7, Z, out, NN);
}

// Round 8
// 394.799 us; speedup vs baseline: 1.3559x; 1.0367x over previous
//
#include <hip/hip_runtime.h>
#include <hip/hip_fp16.h>
#include <math.h>

#define NN 50000
#define NE 800000
#define EPSV 1e-5f
#define SCAN_NB 49   // ceil(NN / 1024)

// ---------------- degree count ----------------
__global__ void deg_kernel(const int* __restrict__ dst, int* __restrict__ deg, int E) {
    int e = blockIdx.x * blockDim.x + threadIdx.x;
    if (e < E) atomicAdd(&deg[dst[e]], 1);
}

// ---------------- 3-phase grid-wide exclusive scan of deg -> rowptr, cursor ----------------
__global__ void scan_phaseA(const int* __restrict__ deg, int* __restrict__ blocksum) {
    __shared__ int wsums[4];
    int t = threadIdx.x;
    int base = blockIdx.x * 1024 + t * 4;
    int s = 0;
    if (base + 3 < NN) {
        int4 d = *reinterpret_cast<const int4*>(deg + base);
        s = d.x + d.y + d.z + d.w;
    } else {
        for (int j = 0; j < 4; ++j) if (base + j < NN) s += deg[base + j];
    }
#pragma unroll
    for (int o = 1; o < 64; o <<= 1) s += __shfl_xor(s, o, 64);
    if ((t & 63) == 0) wsums[t >> 6] = s;
    __syncthreads();
    if (t == 0) blocksum[blockIdx.x] = wsums[0] + wsums[1] + wsums[2] + wsums[3];
}

__global__ void scan_phaseB(int* __restrict__ blocksum) {
    int t = threadIdx.x;  // 64 threads
    int v = (t < SCAN_NB) ? blocksum[t] : 0;
    int incl = v;
#pragma unroll
    for (int o = 1; o < 64; o <<= 1) {
        int nv = __shfl_up(incl, o, 64);
        if (t >= o) incl += nv;
    }
    if (t < SCAN_NB) blocksum[t] = incl - v;  // exclusive
}

__global__ void scan_phaseC(const int* __restrict__ deg, const int* __restrict__ blocksum,
                            int* __restrict__ rowptr, int* __restrict__ cursor) {
    __shared__ int woff[4];
    int t = threadIdx.x;
    int base = blockIdx.x * 1024 + t * 4;
    int d0 = 0, d1 = 0, d2 = 0, d3 = 0;
    if (base + 3 < NN) {
        int4 d = *reinterpret_cast<const int4*>(deg + base);
        d0 = d.x; d1 = d.y; d2 = d.z; d3 = d.w;
    } else {
        if (base + 0 < NN) d0 = deg[base + 0];
        if (base + 1 < NN) d1 = deg[base + 1];
        if (base + 2 < NN) d2 = deg[base + 2];
        if (base + 3 < NN) d3 = deg[base + 3];
    }
    int ts = d0 + d1 + d2 + d3;
    int lane = t & 63, w = t >> 6;
    int incl = ts;
#pragma unroll
    for (int o = 1; o < 64; o <<= 1) {
        int nv = __shfl_up(incl, o, 64);
        if (lane >= o) incl += nv;
    }
    if (lane == 63) woff[w] = incl;
    __syncthreads();
    if (t == 0) {
        int r = 0;
#pragma unroll
        for (int i = 0; i < 4; ++i) { int v = woff[i]; woff[i] = r; r += v; }
    }
    __syncthreads();
    int run = blocksum[blockIdx.x] + woff[w] + incl - ts;
    int r0 = run, r1 = r0 + d0, r2 = r1 + d1, r3 = r2 + d2;
    if (base + 3 < NN) {
        int4 rv; rv.x = r0; rv.y = r1; rv.z = r2; rv.w = r3;
        *reinterpret_cast<int4*>(rowptr + base) = rv;
        *reinterpret_cast<int4*>(cursor + base) = rv;
    } else {
        if (base + 0 < NN) { rowptr[base + 0] = r0; cursor[base + 0] = r0; }
        if (base + 1 < NN) { rowptr[base + 1] = r1; cursor[base + 1] = r1; }
        if (base + 2 < NN) { rowptr[base + 2] = r2; cursor[base + 2] = r2; }
    }
    if (blockIdx.x == 0 && t == 0) rowptr[NN] = NE;  // total degree is always E
}

// ---------------- bucket edges by dst: packed 8 B record ----------------
__global__ void fill_kernel(const int* __restrict__ src, const int* __restrict__ dst,
                            const float* __restrict__ attr, int* __restrict__ cursor,
                            int2* __restrict__ es, int E) {
    int e = blockIdx.x * blockDim.x + threadIdx.x;
    if (e >= E) return;
    int pos = atomicAdd(&cursor[dst[e]], 1);
    int2 rec;
    rec.x = src[e];
    rec.y = __float_as_int(attr[e]);
    es[pos] = rec;
}

// ---------------- matmul: lane = output channel, weights VGPR-resident, x via s_load ----------------
// blockIdx.y: 0 -> Ya (fp16), 1 -> Yb (fp16), 2 -> Z = x@R + B (fp32)
template<int CIN>
__global__ __launch_bounds__(256) void matmulW_kernel(const float* __restrict__ x,
                               const float* __restrict__ W,   // (2, CIN, 64)
                               const float* __restrict__ R,   // (CIN, 64)
                               const float* __restrict__ Bb,  // (64)
                               __half* __restrict__ Ya,
                               __half* __restrict__ Yb,
                               float* __restrict__ Z,
                               int n_nodes) {
    const int lane = threadIdx.x & 63;
    const int wid  = __builtin_amdgcn_readfirstlane(threadIdx.x >> 6);  // wave-uniform
    const int part = blockIdx.y;  // 0: a, 1: b, 2: z
    const float* M = (part == 0) ? W : (part == 1) ? (W + CIN * 64) : R;
    // weight column for this lane, VGPR-resident for the whole wave lifetime
    float wv[CIN];
#pragma unroll
    for (int c = 0; c < CIN; ++c) wv[c] = M[c * 64 + lane];
    float bias = (part == 2) ? Bb[lane] : 0.f;

    const int CHUNK = 32;
    int n0 = (blockIdx.x * 4 + wid) * CHUNK;
    int n1 = n0 + CHUNK; if (n1 > n_nodes) n1 = n_nodes;
    for (int n = n0; n < n1; ++n) {
        const float* xr = x + (size_t)n * CIN;  // wave-uniform address -> s_load
        float acc = 0.f;
#pragma unroll
        for (int c = 0; c < CIN; ++c) acc = fmaf(xr[c], wv[c], acc);
        if (part == 0)      Ya[(size_t)n * 64 + lane] = __float2half(acc);
        else if (part == 1) Yb[(size_t)n * 64 + lane] = __float2half(acc);
        else                Z[(size_t)n * 64 + lane] = acc + bias;
    }
}

// ---------------- layer-2 matmul: thread = node, blockIdx.y = {a,b,z} part ----------------
__global__ __launch_bounds__(256) void matmul7_kernel(const float* __restrict__ x,   // (n,64)
                               const float* __restrict__ W,   // (2,64,7)
                               const float* __restrict__ R,   // (64,7)
                               const float* __restrict__ Bb,  // (7)
                               float* __restrict__ Yab7,      // (n,7,2)
                               float* __restrict__ Z,         // (n,7)
                               int n_nodes) {
    int n = blockIdx.x * blockDim.x + threadIdx.x;
    if (n >= n_nodes) return;
    const int part = blockIdx.y;  // 0: a, 1: b, 2: z
    const float* M = (part == 0) ? W : (part == 1) ? (W + 448) : R;
    const float* xr = x + (size_t)n * 64;
    float acc[7];
#pragma unroll
    for (int j = 0; j < 7; ++j) acc[j] = 0.f;
#pragma unroll 2
    for (int c0 = 0; c0 < 64; c0 += 4) {
        float4 xv4 = *reinterpret_cast<const float4*>(xr + c0);
        float xv[4] = { xv4.x, xv4.y, xv4.z, xv4.w };
#pragma unroll
        for (int cc = 0; cc < 4; ++cc) {
            float xv_ = xv[cc];
            int c = c0 + cc;
#pragma unroll
            for (int j = 0; j < 7; ++j) acc[j] = fmaf(xv_, M[c * 7 + j], acc[j]);
        }
    }
    if (part == 0) {
#pragma unroll
        for (int j = 0; j < 7; ++j) Yab7[(size_t)n * 14 + 2 * j] = acc[j];
    } else if (part == 1) {
#pragma unroll
        for (int j = 0; j < 7; ++j) Yab7[(size_t)n * 14 + 2 * j + 1] = acc[j];
    } else {
#pragma unroll
        for (int j = 0; j < 7; ++j) Z[(size_t)n * 7 + j] = acc[j] + Bb[j];
    }
}

// ---------------- gather (H=64, fp16 Ya/Yb) + BN + ELU fused: one wave per node ----------------
__global__ void gather64_kernel(const int* __restrict__ rowptr,
                                const int2* __restrict__ es,
                                const __half* __restrict__ Ya,
                                const __half* __restrict__ Yb,
                                const float* __restrict__ Z,
                                const float* __restrict__ G, const float* __restrict__ BE,
                                const float* __restrict__ RM, const float* __restrict__ RV,
                                float* __restrict__ h, int n_nodes) {
    int n = (blockIdx.x * blockDim.x + threadIdx.x) >> 6;
    int lane = threadIdx.x & 63;
    if (n >= n_nodes) return;
    int beg = rowptr[n], end = rowptr[n + 1];
    float acc0 = 0.f, acc1 = 0.f;
    int i = beg;
    for (; i + 1 < end; i += 2) {
        int2 e0 = es[i];
        int2 e1 = es[i + 1];
        float u0 = __int_as_float(e0.y);
        float u1 = __int_as_float(e1.y);
        float a0 = __half2float(Ya[(size_t)e0.x * 64 + lane]);
        float b0 = __half2float(Yb[(size_t)e0.x * 64 + lane]);
        float a1 = __half2float(Ya[(size_t)e1.x * 64 + lane]);
        float b1 = __half2float(Yb[(size_t)e1.x * 64 + lane]);
        acc0 += (1.f - u0) * a0 + u0 * b0;
        acc1 += (1.f - u1) * a1 + u1 * b1;
    }
    if (i < end) {
        int2 e0 = es[i];
        float u0 = __int_as_float(e0.y);
        float a0 = __half2float(Ya[(size_t)e0.x * 64 + lane]);
        float b0 = __half2float(Yb[(size_t)e0.x * 64 + lane]);
        acc0 += (1.f - u0) * a0 + u0 * b0;
    }
    float acc = acc0 + acc1;
    float degv = (float)(end - beg);
    if (degv < 1.f) degv = 1.f;
    float v = acc / degv + Z[n * 64 + lane];
    v = (v - RM[lane]) * rsqrtf(RV[lane] + EPSV) * G[lane] + BE[lane];
    h[n * 64 + lane] = v > 0.f ? v : expm1f(v);
}

// ---------------- gather (C=7) + log_softmax fused: 8 lanes per node ----------------
__global__ void gather7_final_kernel(const int* __restrict__ rowptr,
                                     const int2* __restrict__ es,
                                     const float* __restrict__ Yab7,  // (n,7,2)
                                     const float* __restrict__ Z,
                                     float* __restrict__ out, int n_nodes) {
    int t = blockIdx.x * blockDim.x + threadIdx.x;
    int n = t >> 3;
    int c = t & 7;
    if (n >= n_nodes) return;
    int beg = rowptr[n], end = rowptr[n + 1];
    float acc = 0.f;
    if (c < 7) {
        for (int i = beg; i < end; ++i) {
            int2 e0 = es[i];
            float u = __int_as_float(e0.y);
            float2 ab = *reinterpret_cast<const float2*>(Yab7 + (size_t)e0.x * 14 + 2 * c);
            acc += (1.f - u) * ab.x + u * ab.y;
        }
    }
    float degv = (float)(end - beg);
    if (degv < 1.f) degv = 1.f;
    float v = (c < 7) ? (acc / degv + Z[n * 7 + c]) : -1e30f;
    float m = v;
#pragma unroll
    for (int o = 1; o < 8; o <<= 1) m = fmaxf(m, __shfl_xor(m, o, 8));
    float ex = (c < 7) ? expf(v - m) : 0.f;
    float ssum = ex;
#pragma unroll
    for (int o = 1; o < 8; o <<= 1) ssum += __shfl_xor(ssum, o, 8);
    if (c < 7) out[n * 7 + c] = v - m - logf(ssum);
}

extern "C" void kernel_launch(void* const* d_in, const int* in_sizes, int n_in,
                              void* d_out, int out_size, void* d_ws, size_t ws_size,
                              hipStream_t stream) {
    const float* x    = (const float*)d_in[0];
    const int*   ei   = (const int*)d_in[1];
    const float* attr = (const float*)d_in[2];
    const float* W0 = (const float*)d_in[3];
    const float* R0 = (const float*)d_in[4];
    const float* B0 = (const float*)d_in[5];
    const float* W1 = (const float*)d_in[6];
    const float* R1 = (const float*)d_in[7];
    const float* B1 = (const float*)d_in[8];
    const float* W2 = (const float*)d_in[9];
    const float* R2 = (const float*)d_in[10];
    const float* B2 = (const float*)d_in[11];
    const float* G0  = (const float*)d_in[12];
    const float* BE0 = (const float*)d_in[13];
    const float* RM0 = (const float*)d_in[14];
    const float* RV0 = (const float*)d_in[15];
    const float* G1  = (const float*)d_in[16];
    const float* BE1 = (const float*)d_in[17];
    const float* RM1 = (const float*)d_in[18];
    const float* RV1 = (const float*)d_in[19];

    const int* src = ei;
    const int* dst = ei + NE;
    float* out = (float*)d_out;

    // workspace layout
    char* ws = (char*)d_ws;
    size_t off = 0;
    auto alloc = [&](size_t bytes) { char* p = ws + off; off += (bytes + 255) & ~size_t(255); return p; };
    int*    deg      = (int*)   alloc(NN * sizeof(int));
    int*    rowptr   = (int*)   alloc((NN + 1) * sizeof(int));
    int*    cursor   = (int*)   alloc(NN * sizeof(int));
    int*    blocksum = (int*)   alloc(SCAN_NB * sizeof(int));
    int2*   es       = (int2*)  alloc((size_t)NE * sizeof(int2));
    __half* Ya       = (__half*)alloc((size_t)NN * 64 * sizeof(__half));
    __half* Yb       = (__half*)alloc((size_t)NN * 64 * sizeof(__half));
    float*  Yab7     = (float*) alloc((size_t)NN * 14 * sizeof(float));
    float*  Z        = (float*) alloc((size_t)NN * 64 * sizeof(float));
    float*  h        = (float*) alloc((size_t)NN * 64 * sizeof(float));

    const int B = 256;
    const int gE    = (NE + B - 1) / B;
    const int gN64  = (NN * 64 + B - 1) / B;
    const int gN    = (NN + B - 1) / B;
    const int gN8   = (NN * 8 + B - 1) / B;
    const int gW    = (NN + 4 * 32 - 1) / (4 * 32);  // 4 waves/block, 32 nodes/wave

    // ---- CSR build (once, reused by all 3 layers) ----
    hipMemsetAsync(deg, 0, NN * sizeof(int), stream);
    deg_kernel<<<gE, B, 0, stream>>>(dst, deg, NE);
    scan_phaseA<<<SCAN_NB, 256, 0, stream>>>(deg, blocksum);
    scan_phaseB<<<1, 64, 0, stream>>>(blocksum);
    scan_phaseC<<<SCAN_NB, 256, 0, stream>>>(deg, blocksum, rowptr, cursor);
    fill_kernel<<<gE, B, 0, stream>>>(src, dst, attr, cursor, es, NE);

    // ---- layer 0: F_IN=32 -> H=64 ----
    matmulW_kernel<32><<<dim3(gW, 3), B, 0, stream>>>(x, W0, R0, B0, Ya, Yb, Z, NN);
    gather64_kernel<<<gN64, B, 0, stream>>>(rowptr, es, Ya, Yb, Z, G0, BE0, RM0, RV0, h, NN);

    // ---- layer 1: H=64 -> H=64 ----
    matmulW_kernel<64><<<dim3(gW, 3), B, 0, stream>>>(h, W1, R1, B1, Ya, Yb, Z, NN);
    gather64_kernel<<<gN64, B, 0, stream>>>(rowptr, es, Ya, Yb, Z, G1, BE1, RM1, RV1, h, NN);

    // ---- layer 2: H=64 -> C=7, then log_softmax ----
    matmul7_kernel<<<dim3(gN, 3), B, 0, stream>>>(h, W2, R2, B2, Yab7, Z, NN);
    gather7_final_kernel<<<gN8, B, 0, stream>>>(rowptr, es, Yab7, Z, out, NN);
}

// Round 9
// 367.452 us; speedup vs baseline: 1.4568x; 1.0744x over previous
//
#include <hip/hip_runtime.h>
#include <hip/hip_fp16.h>
#include <math.h>

#define NN 50000
#define NE 800000
#define EPSV 1e-5f
#define SCAN_NB 49   // ceil(NN / 1024)

typedef _Float16 h2f __attribute__((ext_vector_type(2)));

// ---------------- degree count ----------------
__global__ void deg_kernel(const int* __restrict__ dst, int* __restrict__ deg, int E) {
    int e = blockIdx.x * blockDim.x + threadIdx.x;
    if (e < E) atomicAdd(&deg[dst[e]], 1);
}

// ---------------- 3-phase grid-wide exclusive scan of deg -> rowptr, cursor ----------------
__global__ void scan_phaseA(const int* __restrict__ deg, int* __restrict__ blocksum) {
    __shared__ int wsums[4];
    int t = threadIdx.x;
    int base = blockIdx.x * 1024 + t * 4;
    int s = 0;
    if (base + 3 < NN) {
        int4 d = *reinterpret_cast<const int4*>(deg + base);
        s = d.x + d.y + d.z + d.w;
    } else {
        for (int j = 0; j < 4; ++j) if (base + j < NN) s += deg[base + j];
    }
#pragma unroll
    for (int o = 1; o < 64; o <<= 1) s += __shfl_xor(s, o, 64);
    if ((t & 63) == 0) wsums[t >> 6] = s;
    __syncthreads();
    if (t == 0) blocksum[blockIdx.x] = wsums[0] + wsums[1] + wsums[2] + wsums[3];
}

__global__ void scan_phaseB(int* __restrict__ blocksum) {
    int t = threadIdx.x;  // 64 threads
    int v = (t < SCAN_NB) ? blocksum[t] : 0;
    int incl = v;
#pragma unroll
    for (int o = 1; o < 64; o <<= 1) {
        int nv = __shfl_up(incl, o, 64);
        if (t >= o) incl += nv;
    }
    if (t < SCAN_NB) blocksum[t] = incl - v;  // exclusive
}

__global__ void scan_phaseC(const int* __restrict__ deg, const int* __restrict__ blocksum,
                            int* __restrict__ rowptr, int* __restrict__ cursor) {
    __shared__ int woff[4];
    int t = threadIdx.x;
    int base = blockIdx.x * 1024 + t * 4;
    int d0 = 0, d1 = 0, d2 = 0, d3 = 0;
    if (base + 3 < NN) {
        int4 d = *reinterpret_cast<const int4*>(deg + base);
        d0 = d.x; d1 = d.y; d2 = d.z; d3 = d.w;
    } else {
        if (base + 0 < NN) d0 = deg[base + 0];
        if (base + 1 < NN) d1 = deg[base + 1];
        if (base + 2 < NN) d2 = deg[base + 2];
        if (base + 3 < NN) d3 = deg[base + 3];
    }
    int ts = d0 + d1 + d2 + d3;
    int lane = t & 63, w = t >> 6;
    int incl = ts;
#pragma unroll
    for (int o = 1; o < 64; o <<= 1) {
        int nv = __shfl_up(incl, o, 64);
        if (lane >= o) incl += nv;
    }
    if (lane == 63) woff[w] = incl;
    __syncthreads();
    if (t == 0) {
        int r = 0;
#pragma unroll
        for (int i = 0; i < 4; ++i) { int v = woff[i]; woff[i] = r; r += v; }
    }
    __syncthreads();
    int run = blocksum[blockIdx.x] + woff[w] + incl - ts;
    int r0 = run, r1 = r0 + d0, r2 = r1 + d1, r3 = r2 + d2;
    if (base + 3 < NN) {
        int4 rv; rv.x = r0; rv.y = r1; rv.z = r2; rv.w = r3;
        *reinterpret_cast<int4*>(rowptr + base) = rv;
        *reinterpret_cast<int4*>(cursor + base) = rv;
    } else {
        if (base + 0 < NN) { rowptr[base + 0] = r0; cursor[base + 0] = r0; }
        if (base + 1 < NN) { rowptr[base + 1] = r1; cursor[base + 1] = r1; }
        if (base + 2 < NN) { rowptr[base + 2] = r2; cursor[base + 2] = r2; }
    }
    if (blockIdx.x == 0 && t == 0) rowptr[NN] = NE;  // total degree is always E
}

// ---------------- bucket edges by dst: {src, packed half2(1-u, u)} ----------------
__global__ void fill_kernel(const int* __restrict__ src, const int* __restrict__ dst,
                            const float* __restrict__ attr, int* __restrict__ cursor,
                            int2* __restrict__ es, int E) {
    int e = blockIdx.x * blockDim.x + threadIdx.x;
    if (e >= E) return;
    int pos = atomicAdd(&cursor[dst[e]], 1);
    float u = attr[e];
    __half2 p = __floats2half2_rn(1.f - u, u);
    int2 rec;
    rec.x = src[e];
    rec.y = *reinterpret_cast<int*>(&p);
    es[pos] = rec;
}

// ---------------- matmul: lane = output channel, weights VGPR-resident, x via s_load ----------------
// blockIdx.y: 0 -> YabH (half2{a,b} interleaved), 1 -> Z = x@R + B (fp32)
template<int CIN>
__global__ __launch_bounds__(256) void matmulW_kernel(const float* __restrict__ x,
                               const float* __restrict__ W,   // (2, CIN, 64)
                               const float* __restrict__ R,   // (CIN, 64)
                               const float* __restrict__ Bb,  // (64)
                               __half2* __restrict__ YabH,
                               float* __restrict__ Z,
                               int n_nodes) {
    const int lane = threadIdx.x & 63;
    const int wid  = __builtin_amdgcn_readfirstlane(threadIdx.x >> 6);  // wave-uniform
    const int part = blockIdx.y;  // 0: ab, 1: z

    const int CHUNK = 32;
    int n0 = (blockIdx.x * 4 + wid) * CHUNK;
    int n1 = n0 + CHUNK; if (n1 > n_nodes) n1 = n_nodes;

    if (part == 0) {
        float wa[CIN], wb[CIN];
#pragma unroll
        for (int c = 0; c < CIN; ++c) {
            wa[c] = W[c * 64 + lane];
            wb[c] = W[CIN * 64 + c * 64 + lane];
        }
        for (int n = n0; n < n1; ++n) {
            const float* xr = x + (size_t)n * CIN;  // wave-uniform -> s_load
            float acca = 0.f, accb = 0.f;
#pragma unroll
            for (int c = 0; c < CIN; ++c) {
                float xv = xr[c];
                acca = fmaf(xv, wa[c], acca);
                accb = fmaf(xv, wb[c], accb);
            }
            YabH[(size_t)n * 64 + lane] = __floats2half2_rn(acca, accb);
        }
    } else {
        float wr[CIN];
#pragma unroll
        for (int c = 0; c < CIN; ++c) wr[c] = R[c * 64 + lane];
        float bias = Bb[lane];
        for (int n = n0; n < n1; ++n) {
            const float* xr = x + (size_t)n * CIN;
            float acc = 0.f;
#pragma unroll
            for (int c = 0; c < CIN; ++c) acc = fmaf(xr[c], wr[c], acc);
            Z[(size_t)n * 64 + lane] = acc + bias;
        }
    }
}

// ---------------- layer-2 matmul: thread = node, blockIdx.y = {a,b,z} part ----------------
__global__ __launch_bounds__(256) void matmul7_kernel(const float* __restrict__ x,   // (n,64)
                               const float* __restrict__ W,   // (2,64,7)
                               const float* __restrict__ R,   // (64,7)
                               const float* __restrict__ Bb,  // (7)
                               float* __restrict__ Yab7,      // (n,7,2)
                               float* __restrict__ Z,         // (n,7)
                               int n_nodes) {
    int n = blockIdx.x * blockDim.x + threadIdx.x;
    if (n >= n_nodes) return;
    const int part = blockIdx.y;  // 0: a, 1: b, 2: z
    const float* M = (part == 0) ? W : (part == 1) ? (W + 448) : R;
    const float* xr = x + (size_t)n * 64;
    float acc[7];
#pragma unroll
    for (int j = 0; j < 7; ++j) acc[j] = 0.f;
#pragma unroll 2
    for (int c0 = 0; c0 < 64; c0 += 4) {
        float4 xv4 = *reinterpret_cast<const float4*>(xr + c0);
        float xv[4] = { xv4.x, xv4.y, xv4.z, xv4.w };
#pragma unroll
        for (int cc = 0; cc < 4; ++cc) {
            float xv_ = xv[cc];
            int c = c0 + cc;
#pragma unroll
            for (int j = 0; j < 7; ++j) acc[j] = fmaf(xv_, M[c * 7 + j], acc[j]);
        }
    }
    if (part == 0) {
#pragma unroll
        for (int j = 0; j < 7; ++j) Yab7[(size_t)n * 14 + 2 * j] = acc[j];
    } else if (part == 1) {
#pragma unroll
        for (int j = 0; j < 7; ++j) Yab7[(size_t)n * 14 + 2 * j + 1] = acc[j];
    } else {
#pragma unroll
        for (int j = 0; j < 7; ++j) Z[(size_t)n * 7 + j] = acc[j] + Bb[j];
    }
}

// ---------------- gather (H=64) + BN + ELU: one wave per node, fdot2 inner op ----------------
__global__ void gather64_kernel(const int* __restrict__ rowptr,
                                const int2* __restrict__ es,
                                const __half2* __restrict__ YabH,
                                const float* __restrict__ Z,
                                const float* __restrict__ G, const float* __restrict__ BE,
                                const float* __restrict__ RM, const float* __restrict__ RV,
                                float* __restrict__ h, int n_nodes) {
    int n = (blockIdx.x * blockDim.x + threadIdx.x) >> 6;
    int lane = threadIdx.x & 63;
    if (n >= n_nodes) return;
    int beg = rowptr[n], end = rowptr[n + 1];
    float acc0 = 0.f, acc1 = 0.f, acc2 = 0.f, acc3 = 0.f;
    int i = beg;
    for (; i + 3 < end; i += 4) {
        int2 e0 = es[i];
        int2 e1 = es[i + 1];
        int2 e2 = es[i + 2];
        int2 e3 = es[i + 3];
        __half2 v0 = YabH[(size_t)e0.x * 64 + lane];
        __half2 v1 = YabH[(size_t)e1.x * 64 + lane];
        __half2 v2 = YabH[(size_t)e2.x * 64 + lane];
        __half2 v3 = YabH[(size_t)e3.x * 64 + lane];
        acc0 = __builtin_amdgcn_fdot2(__builtin_bit_cast(h2f, v0), __builtin_bit_cast(h2f, e0.y), acc0, false);
        acc1 = __builtin_amdgcn_fdot2(__builtin_bit_cast(h2f, v1), __builtin_bit_cast(h2f, e1.y), acc1, false);
        acc2 = __builtin_amdgcn_fdot2(__builtin_bit_cast(h2f, v2), __builtin_bit_cast(h2f, e2.y), acc2, false);
        acc3 = __builtin_amdgcn_fdot2(__builtin_bit_cast(h2f, v3), __builtin_bit_cast(h2f, e3.y), acc3, false);
    }
    for (; i < end; ++i) {
        int2 e0 = es[i];
        __half2 v0 = YabH[(size_t)e0.x * 64 + lane];
        acc0 = __builtin_amdgcn_fdot2(__builtin_bit_cast(h2f, v0), __builtin_bit_cast(h2f, e0.y), acc0, false);
    }
    float acc = (acc0 + acc1) + (acc2 + acc3);
    float degv = (float)(end - beg);
    if (degv < 1.f) degv = 1.f;
    float v = acc / degv + Z[n * 64 + lane];
    v = (v - RM[lane]) * rsqrtf(RV[lane] + EPSV) * G[lane] + BE[lane];
    h[n * 64 + lane] = v > 0.f ? v : expm1f(v);
}

// ---------------- gather (C=7) + log_softmax fused: 8 lanes per node ----------------
__global__ void gather7_final_kernel(const int* __restrict__ rowptr,
                                     const int2* __restrict__ es,
                                     const float* __restrict__ Yab7,  // (n,7,2)
                                     const float* __restrict__ Z,
                                     float* __restrict__ out, int n_nodes) {
    int t = blockIdx.x * blockDim.x + threadIdx.x;
    int n = t >> 3;
    int c = t & 7;
    if (n >= n_nodes) return;
    int beg = rowptr[n], end = rowptr[n + 1];
    float acc = 0.f;
    if (c < 7) {
        for (int i = beg; i < end; ++i) {
            int2 e0 = es[i];
            h2f u2 = __builtin_bit_cast(h2f, e0.y);
            float w0 = (float)u2.x;
            float w1 = (float)u2.y;
            float2 ab = *reinterpret_cast<const float2*>(Yab7 + (size_t)e0.x * 14 + 2 * c);
            acc += w0 * ab.x + w1 * ab.y;
        }
    }
    float degv = (float)(end - beg);
    if (degv < 1.f) degv = 1.f;
    float v = (c < 7) ? (acc / degv + Z[n * 7 + c]) : -1e30f;
    float m = v;
#pragma unroll
    for (int o = 1; o < 8; o <<= 1) m = fmaxf(m, __shfl_xor(m, o, 8));
    float ex = (c < 7) ? expf(v - m) : 0.f;
    float ssum = ex;
#pragma unroll
    for (int o = 1; o < 8; o <<= 1) ssum += __shfl_xor(ssum, o, 8);
    if (c < 7) out[n * 7 + c] = v - m - logf(ssum);
}

extern "C" void kernel_launch(void* const* d_in, const int* in_sizes, int n_in,
                              void* d_out, int out_size, void* d_ws, size_t ws_size,
                              hipStream_t stream) {
    const float* x    = (const float*)d_in[0];
    const int*   ei   = (const int*)d_in[1];
    const float* attr = (const float*)d_in[2];
    const float* W0 = (const float*)d_in[3];
    const float* R0 = (const float*)d_in[4];
    const float* B0 = (const float*)d_in[5];
    const float* W1 = (const float*)d_in[6];
    const float* R1 = (const float*)d_in[7];
    const float* B1 = (const float*)d_in[8];
    const float* W2 = (const float*)d_in[9];
    const float* R2 = (const float*)d_in[10];
    const float* B2 = (const float*)d_in[11];
    const float* G0  = (const float*)d_in[12];
    const float* BE0 = (const float*)d_in[13];
    const float* RM0 = (const float*)d_in[14];
    const float* RV0 = (const float*)d_in[15];
    const float* G1  = (const float*)d_in[16];
    const float* BE1 = (const float*)d_in[17];
    const float* RM1 = (const float*)d_in[18];
    const float* RV1 = (const float*)d_in[19];

    const int* src = ei;
    const int* dst = ei + NE;
    float* out = (float*)d_out;

    // workspace layout
    char* ws = (char*)d_ws;
    size_t off = 0;
    auto alloc = [&](size_t bytes) { char* p = ws + off; off += (bytes + 255) & ~size_t(255); return p; };
    int*     deg      = (int*)    alloc(NN * sizeof(int));
    int*     rowptr   = (int*)    alloc((NN + 1) * sizeof(int));
    int*     cursor   = (int*)    alloc(NN * sizeof(int));
    int*     blocksum = (int*)    alloc(SCAN_NB * sizeof(int));
    int2*    es       = (int2*)   alloc((size_t)NE * sizeof(int2));
    __half2* YabH     = (__half2*)alloc((size_t)NN * 64 * sizeof(__half2));
    float*   Yab7     = (float*)  alloc((size_t)NN * 14 * sizeof(float));
    float*   Z        = (float*)  alloc((size_t)NN * 64 * sizeof(float));
    float*   h        = (float*)  alloc((size_t)NN * 64 * sizeof(float));

    const int B = 256;
    const int gE    = (NE + B - 1) / B;
    const int gN64  = (NN * 64 + B - 1) / B;
    const int gN    = (NN + B - 1) / B;
    const int gN8   = (NN * 8 + B - 1) / B;
    const int gW    = (NN + 4 * 32 - 1) / (4 * 32);  // 4 waves/block, 32 nodes/wave

    // ---- CSR build (once, reused by all 3 layers) ----
    hipMemsetAsync(deg, 0, NN * sizeof(int), stream);
    deg_kernel<<<gE, B, 0, stream>>>(dst, deg, NE);
    scan_phaseA<<<SCAN_NB, 256, 0, stream>>>(deg, blocksum);
    scan_phaseB<<<1, 64, 0, stream>>>(blocksum);
    scan_phaseC<<<SCAN_NB, 256, 0, stream>>>(deg, blocksum, rowptr, cursor);
    fill_kernel<<<gE, B, 0, stream>>>(src, dst, attr, cursor, es, NE);

    // ---- layer 0: F_IN=32 -> H=64 ----
    matmulW_kernel<32><<<dim3(gW, 2), B, 0, stream>>>(x, W0, R0, B0, YabH, Z, NN);
    gather64_kernel<<<gN64, B, 0, stream>>>(rowptr, es, YabH, Z, G0, BE0, RM0, RV0, h, NN);

    // ---- layer 1: H=64 -> H=64 ----
    matmulW_kernel<64><<<dim3(gW, 2), B, 0, stream>>>(h, W1, R1, B1, YabH, Z, NN);
    gather64_kernel<<<gN64, B, 0, stream>>>(rowptr, es, YabH, Z, G1, BE1, RM1, RV1, h, NN);

    // ---- layer 2: H=64 -> C=7, then log_softmax ----
    matmul7_kernel<<<dim3(gN, 3), B, 0, stream>>>(h, W2, R2, B2, Yab7, Z, NN);
    gather7_final_kernel<<<gN8, B, 0, stream>>>(rowptr, es, Yab7, Z, out, NN);
}